// Round 5
// baseline (135.867 us; speedup 1.0000x reference)
//
#include <hip/hip_runtime.h>
#include <hip/hip_bf16.h>
#include <math.h>
#include <string.h>

#define BB   16
#define NN   128
#define NCC  32
#define HH   256
#define AA   64
#define DEGN 3
#define BNR  (BB*NN)   // 2048 rows

typedef __bf16 bf16x8 __attribute__((ext_vector_type(8)));
typedef float  f32x16 __attribute__((ext_vector_type(16)));

// ---------------------------------------------------------------------------
// Kernel 1: masked mean-pool of condition vectors -> pooled [B,H]
// ---------------------------------------------------------------------------
__global__ __launch_bounds__(256) void k_pool(const float* __restrict__ cond,
                                              const float* __restrict__ cmask,
                                              float* __restrict__ pooled) {
    int b = blockIdx.x, h = threadIdx.x;
    float s = 0.f, ms = 0.f;
    for (int c = 0; c < NCC; ++c) {
        float mk = cmask[b * NCC + c];
        s  += cond[(b * NCC + c) * HH + h] * mk;
        ms += mk;
    }
    pooled[b * HH + h] = s / fmaxf(ms, 1.0f);
}

// ---------------------------------------------------------------------------
// Kernel 2: dv[d,b,:] = pooled[b,:] @ Wc[d]  (also writes dvs output)
// ---------------------------------------------------------------------------
__global__ __launch_bounds__(256) void k_dv(const float* __restrict__ pooled,
                                            const float* __restrict__ Wc,
                                            float* __restrict__ dv,
                                            float* __restrict__ dv_out) {
    int d = blockIdx.x / BB, b = blockIdx.x % BB, h = threadIdx.x;
    const float* Wd = Wc + (size_t)d * HH * HH;
    const float* pb = pooled + b * HH;
    float acc = 0.f;
    for (int k = 0; k < HH; ++k) acc += pb[k] * Wd[k * HH + h];
    int idx = (d * BB + b) * HH + h;
    dv[idx]     = acc;
    dv_out[idx] = acc;
}

// ---------------------------------------------------------------------------
// Kernel 3: hbuf[d,row,:] = gelu_tanh(x[row,:] @ W1[d] + b1[d] + dv[d,b])
// ---------------------------------------------------------------------------
__global__ __launch_bounds__(256) void k_enc(const float* __restrict__ x,
                                             const float* __restrict__ W1,
                                             const float* __restrict__ b1,
                                             const float* __restrict__ dv,
                                             float* __restrict__ hbuf) {
    const int RT = BNR / 16;  // 128 row-tiles
    int d = blockIdx.x / RT, rt = blockIdx.x % RT;
    int row0 = rt * 16;
    int h = threadIdx.x;
    __shared__ float xs[16][HH];
    #pragma unroll
    for (int rr = 0; rr < 16; ++rr) xs[rr][h] = x[(row0 + rr) * HH + h];
    __syncthreads();

    float acc[16];
    #pragma unroll
    for (int r = 0; r < 16; ++r) acc[r] = 0.f;

    const float* Wd = W1 + (size_t)d * HH * HH;
    for (int k = 0; k < HH; k += 4) {
        float w0 = Wd[(k + 0) * HH + h], w1 = Wd[(k + 1) * HH + h];
        float w2 = Wd[(k + 2) * HH + h], w3 = Wd[(k + 3) * HH + h];
        #pragma unroll
        for (int r = 0; r < 16; ++r) {
            float4 xv = *(const float4*)&xs[r][k];
            acc[r] += xv.x * w0 + xv.y * w1 + xv.z * w2 + xv.w * w3;
        }
    }
    int b = row0 / NN;
    float add = b1[d * HH + h] + dv[(d * BB + b) * HH + h];
    #pragma unroll
    for (int r = 0; r < 16; ++r) {
        float v = acc[r] + add;
        float u = 0.7978845608028654f * (v + 0.044715f * v * v * v);
        float g = 0.5f * v * (1.0f + tanhf(u));
        hbuf[((size_t)d * BNR + row0 + r) * HH + h] = g;
    }
}

// ---------------------------------------------------------------------------
// Kernel 4: yv[d,row,:] = (hbuf[d,row,:] @ Wlin[d] + blin[d]) * x_mask[row]
// ---------------------------------------------------------------------------
__global__ __launch_bounds__(256) void k_lin(const float* __restrict__ hbuf,
                                             const float* __restrict__ Wlin,
                                             const float* __restrict__ blin,
                                             const float* __restrict__ xmask,
                                             float* __restrict__ yv) {
    const int RT = BNR / 16;
    int d = blockIdx.x / RT, rt = blockIdx.x % RT;
    int row0 = rt * 16;
    int t = threadIdx.x;
    int a = t & 63, rg = t >> 6;
    __shared__ float hs[16][HH];
    for (int e = t; e < 16 * HH; e += 256) {
        int rr = e >> 8, k = e & 255;
        hs[rr][k] = hbuf[((size_t)d * BNR + row0 + rr) * HH + k];
    }
    __syncthreads();

    const float* Wd = Wlin + (size_t)d * HH * AA;
    float acc[4] = {0.f, 0.f, 0.f, 0.f};
    for (int k = 0; k < HH; k += 4) {
        float w0 = Wd[(k + 0) * AA + a], w1 = Wd[(k + 1) * AA + a];
        float w2 = Wd[(k + 2) * AA + a], w3 = Wd[(k + 3) * AA + a];
        #pragma unroll
        for (int rr = 0; rr < 4; ++rr) {
            float4 hv = *(const float4*)&hs[rg * 4 + rr][k];
            acc[rr] += hv.x * w0 + hv.y * w1 + hv.z * w2 + hv.w * w3;
        }
    }
    float bl = blin[d * AA + a];
    #pragma unroll
    for (int rr = 0; rr < 4; ++rr) {
        int row = row0 + rg * 4 + rr;
        yv[((size_t)d * BNR + row) * AA + a] = (acc[rr] + bl) * xmask[row];
    }
}

// ---------------------------------------------------------------------------
// Kernel 5: symmetric contraction, bf16 32x32x16 MFMA, K-split, one x/block.
// out*4096 = A1 B1^T + B1 A1^T + A2 B2^T + B2 A2^T  with (per b,x):
//   A1[r][k] = s0[k]*Y1[r,k] + s1[k]*Y0[r,k]   (k<64)
//   B1[r][k] = Y2[r,k]
//   A2[r][k] = s2[k]*Y0[r,k]
//   B2[r][k] = Y1[r,k]
// Round q stages (Aq,Bq) as bf16 [128][64] in LDS (16KB each, XOR swizzle
// byte ^= (row&7)<<4), then two MFMA passes (roles swapped) accumulate both
// symmetric terms. 32KB LDS -> 4 blocks/CU; no barrier after stores.
// Epilogue: 32x32 C fragments -> each half-wave store = full 128B line.
// ---------------------------------------------------------------------------
__device__ __forceinline__ unsigned int pk2(float lo, float hi) {
    __hip_bfloat162 h2 = __float22bfloat162_rn(make_float2(lo, hi));
    unsigned int u;
    memcpy(&u, &h2, 4);
    return u;
}

#define LROW 128   // bytes per LDS row (64 bf16)

__global__ __launch_bounds__(256, 4) void k_contract(const float* __restrict__ yv,
                                                     float* __restrict__ outp) {
    __shared__ __align__(16) char lds[2 * 128 * LROW];   // U:16KB | V:16KB
    char* Ub = lds;
    char* Vb = lds + 128 * LROW;

    const int t  = threadIdx.x;
    const int bx = blockIdx.x;            // b*N + x
    const int b  = bx >> 7, xr = bx & 127;

    const float* y0p = yv + (size_t)(0 * BNR + b * NN) * AA;
    const float* y1p = yv + (size_t)(1 * BNR + b * NN) * AA;
    const float* y2p = yv + (size_t)(2 * BNR + b * NN) * AA;

    const int lane = t & 63;
    const int wid  = t >> 6;
    const int li   = lane & 31;           // column-pair index (k = 2li, 2li+1)
    const int rh   = lane >> 5;           // row parity

    // per-lane s values; broadcast the pair this lane's columns need
    const float s0 = y0p[xr * AA + lane];
    const float s1 = y1p[xr * AA + lane];
    const float s2 = y2p[xr * AA + lane];
    const float s0a = __shfl(s0, 2 * li), s0b = __shfl(s0, 2 * li + 1);
    const float s1a = __shfl(s1, 2 * li), s1b = __shfl(s1, 2 * li + 1);
    const float s2a = __shfl(s2, 2 * li), s2b = __shfl(s2, 2 * li + 1);

    const int wy  = (wid >> 1) * 64, wz = (wid & 1) * 64;
    const int rl5 = lane & 31, h2v = lane >> 5;

    f32x16 acc[2][2];
    #pragma unroll
    for (int mi = 0; mi < 2; ++mi)
        #pragma unroll
        for (int ni = 0; ni < 2; ++ni)
            #pragma unroll
            for (int e = 0; e < 16; ++e) acc[mi][ni][e] = 0.f;

    #pragma unroll
    for (int round = 0; round < 2; ++round) {
        // ---- stage (Aq, Bq): each wave writes rows wid*32..wid*32+31 ----
        #pragma unroll
        for (int it = 0; it < 16; ++it) {
            const int r   = wid * 32 + it * 2 + rh;
            const int swz = (r & 7) << 4;
            const float2 v0 = *(const float2*)&y0p[r * AA + 2 * li];
            const float2 v1 = *(const float2*)&y1p[r * AA + 2 * li];
            unsigned int av, bv;
            if (round == 0) {
                const float2 v2 = *(const float2*)&y2p[r * AA + 2 * li];
                av = pk2(s0a * v1.x + s1a * v0.x, s0b * v1.y + s1b * v0.y);
                bv = pk2(v2.x, v2.y);
            } else {
                av = pk2(s2a * v0.x, s2b * v0.y);
                bv = pk2(v1.x, v1.y);
            }
            *(unsigned int*)(Ub + r * LROW + ((4 * li) ^ swz)) = av;
            *(unsigned int*)(Vb + r * LROW + ((4 * li) ^ swz)) = bv;
        }
        __syncthreads();

        // ---- two passes: p=0: Aq·Bq^T ; p=1: Bq·Aq^T (swap operand roles) ----
        #pragma unroll
        for (int p = 0; p < 2; ++p) {
            const char* Ua = p ? Vb : Ub;
            const char* Va = p ? Ub : Vb;
            #pragma unroll
            for (int ks = 0; ks < 4; ++ks) {
                bf16x8 af[2], bf[2];
                #pragma unroll
                for (int mi = 0; mi < 2; ++mi) {
                    int row = wy + mi * 32 + rl5;
                    af[mi] = *(const bf16x8*)(Ua + row * LROW +
                              ((ks * 32 + h2v * 16) ^ ((row & 7) << 4)));
                }
                #pragma unroll
                for (int ni = 0; ni < 2; ++ni) {
                    int row = wz + ni * 32 + rl5;
                    bf[ni] = *(const bf16x8*)(Va + row * LROW +
                              ((ks * 32 + h2v * 16) ^ ((row & 7) << 4)));
                }
                #pragma unroll
                for (int mi = 0; mi < 2; ++mi)
                    #pragma unroll
                    for (int ni = 0; ni < 2; ++ni)
                        acc[mi][ni] = __builtin_amdgcn_mfma_f32_32x32x16_bf16(
                            af[mi], bf[ni], acc[mi][ni], 0, 0, 0);
            }
        }
        __syncthreads();   // LDS consumed; safe to restage next round
    }

    // ---- epilogue: 32x32 C layout col=lane&31, row=(e&3)+8*(e>>2)+4*h2v ----
    const float inv = 1.0f / 4096.0f;
    float* osl = outp + (size_t)bx * (NN * NN);
    #pragma unroll
    for (int mi = 0; mi < 2; ++mi) {
        #pragma unroll
        for (int ni = 0; ni < 2; ++ni) {
            const int colb = wz + ni * 32 + rl5;
            #pragma unroll
            for (int e = 0; e < 16; ++e) {
                int rowf = (e & 3) + 8 * (e >> 2) + 4 * h2v;
                osl[(wy + mi * 32 + rowf) * NN + colb] = acc[mi][ni][e] * inv;
            }
        }
    }
}

// ---------------------------------------------------------------------------
extern "C" void kernel_launch(void* const* d_in, const int* in_sizes, int n_in,
                              void* d_out, int out_size, void* d_ws, size_t ws_size,
                              hipStream_t stream) {
    const float* x     = (const float*)d_in[0];
    const float* xmask = (const float*)d_in[1];
    const float* cond  = (const float*)d_in[2];
    const float* cmask = (const float*)d_in[3];
    const float* W1    = (const float*)d_in[4];
    const float* b1    = (const float*)d_in[5];
    const float* Wc    = (const float*)d_in[6];
    const float* Wlin  = (const float*)d_in[7];
    const float* blin  = (const float*)d_in[8];

    float* out = (float*)d_out;
    float* ws  = (float*)d_ws;

    float* pooled = ws;                        // 16*256
    float* dv     = ws + 4096;                 // 3*16*256
    float* hbuf   = ws + 16384;                // 3*2048*256
    float* yv     = ws + 16384 + 1572864;      // 3*2048*64
    float* dv_out = out + (size_t)BB * NN * NN * NN;

    k_pool    <<<dim3(BB),              dim3(256), 0, stream>>>(cond, cmask, pooled);
    k_dv      <<<dim3(DEGN * BB),       dim3(256), 0, stream>>>(pooled, Wc, dv, dv_out);
    k_enc     <<<dim3(DEGN * (BNR/16)), dim3(256), 0, stream>>>(x, W1, b1, dv, hbuf);
    k_lin     <<<dim3(DEGN * (BNR/16)), dim3(256), 0, stream>>>(hbuf, Wlin, blin, xmask, yv);
    k_contract<<<dim3(BNR),             dim3(256), 0, stream>>>(yv, out);
}